// Round 1
// baseline (115.916 us; speedup 1.0000x reference)
//
#include <hip/hip_runtime.h>
#include <cstdint>

// Problem constants (fixed by reference)
#define NB      8
#define NN      4096
#define NCLS    80
#define MAXDET  300
#define CAP     160     // per-(batch,class) list capacity; counts ~49 +/- 7 (16 sigma)

// Output float layout (flat, 16808 elements)
#define OFF_IDX  0
#define OFF_SCR  2400
#define OFF_BOX  4800
#define OFF_CLS  14400
#define OFF_NDT  16800

// Workspace layout (bytes)
#define WS_KSEG  0                          // u64 [NB*NCLS][CAP] kept keys per class (segmented)
#define WS_KNUM  (NB * NCLS * CAP * 8)      // i32 [NB*NCLS] kept count per class (single writer)

// IoU > thr test, matching reference arithmetic exactly (no FMA contraction).
__device__ __forceinline__ bool iou_gt(float c0, float c1, float c2, float c3,
                                       float t0, float t1, float t2, float t3,
                                       float tarea)
{
#pragma clang fp contract(off)
    float xx1 = fmaxf(c0, t0);
    float yy1 = fmaxf(c1, t1);
    float xx2 = fminf(c2, t2);
    float yy2 = fminf(c3, t3);
    float w = xx2 - xx1; w = fmaxf(w, 0.0f);
    float h = yy2 - yy1; h = fmaxf(h, 0.0f);
    float inter = w * h;
    float areac = (c2 - c0) * (c3 - c1);
    float uni = areac + tarea - inter;
    return (inter / uni) > 0.65f;
}

__device__ __forceinline__ uint64_t shfl_xor64(uint64_t x, int m)
{
    unsigned lo = __shfl_xor((unsigned)x, m, 64);
    unsigned hi = __shfl_xor((unsigned)(x >> 32), m, 64);
    return ((uint64_t)hi << 32) | lo;
}

__device__ __forceinline__ void ce64(uint64_t& a, uint64_t& b, bool desc)
{
    uint64_t lo = (a < b) ? a : b;
    uint64_t hi = (a < b) ? b : a;
    a = desc ? hi : lo;
    b = desc ? lo : hi;
}

// ======== K1: fused bin + per-(b,c) NMS. One wave per (batch,class). ========
// Each block scans its batch's scores/classes (L2-resident, shared by the 80
// blocks of that batch), compacts this class's valid keys into LDS, sorts,
// runs greedy NMS, and writes survivors to a PRIVATE segment kseg[bc][.] with
// count knum[bc]. Single-writer everywhere -> no init kernel, poison-proof.
__global__ __launch_bounds__(64)
void k1_bin_nms(const float* __restrict__ scores,
                const float* __restrict__ boxes,
                const int*   __restrict__ classes,
                uint64_t*    __restrict__ kseg,
                int*         __restrict__ knum)
{
    const int bc   = blockIdx.x;
    const int b    = bc / NCLS;
    const int c    = bc - b * NCLS;
    const int lane = threadIdx.x;
    const int bN   = b * NN;
    const uint64_t lmask = (1ull << lane) - 1ull;

    __shared__ uint64_t mem[CAP];
    __shared__ float4   bx_s[132];
    __shared__ float    ar_s[132];
    __shared__ uint64_t keepw[4];
    __shared__ int      nc_s;

    if (lane == 0) nc_s = 0;
    if (lane < 4) keepw[lane] = 0ull;
    __syncthreads();

    // ---- scan batch, compact this class's valid keys into LDS ----
    const float4* s4 = (const float4*)(scores + bN);
    const int4*   c4 = (const int4*)(classes + bN);
#pragma unroll 4
    for (int i = 0; i < (NN / 4) / 64; ++i) {       // 16 iterations
        const int vi = lane + (i << 6);
        const float4 sv = s4[vi];
        const int4   cv = c4[vi];
        const float ss[4] = {sv.x, sv.y, sv.z, sv.w};
        const int   cc[4] = {cv.x, cv.y, cv.z, cv.w};
        const int base = vi << 2;
#pragma unroll
        for (int e = 0; e < 4; ++e) {
            if (cc[e] == c && ss[e] > 0.05f) {
                unsigned u = __float_as_uint(ss[e]);
                unsigned m = (u & 0x80000000u) ? ~u : (u | 0x80000000u);
                uint64_t key = ((uint64_t)m << 32) | (unsigned)(base + e);
                int slot = atomicAdd(&nc_s, 1);
                if (slot < CAP) mem[slot] = key;
            }
        }
    }
    __syncthreads();
    int nc = nc_s > CAP ? CAP : nc_s;
    uint64_t* ks = kseg + (uint64_t)bc * CAP;
    if (nc <= 0) { if (lane == 0) knum[bc] = 0; return; }
    const float4* boxes4 = (const float4*)boxes;

    if (nc <= 64) {
        // ---- fast path: in-wave descending bitonic sort of 64 u64 keys
        uint64_t key = (lane < nc) ? mem[lane] : 0ull;
        for (int k = 2; k <= 64; k <<= 1) {
            bool up = ((lane & k) == 0);
            for (int j = k >> 1; j >= 1; j >>= 1) {
                uint64_t w = shfl_xor64(key, j);
                bool km = (((lane & j) == 0) == up);
                key = km ? (key > w ? key : w) : (key < w ? key : w);
            }
        }
        unsigned idx = (unsigned)key;    // low 32 bits = batch-local index
        float4 bx = make_float4(0, 0, 0, 0);
        float  area = 0.0f;
        if (lane < nc) {
            bx = boxes4[bN + idx];
            {
#pragma clang fp contract(off)
                area = (bx.z - bx.x) * (bx.w - bx.y);
            }
        }
        bx_s[lane] = bx;
        ar_s[lane] = area;
        __syncthreads();
        uint64_t ov = 0;
        for (int j0 = 0; j0 < nc - 1; j0 += 4) {
            float4 t[4]; float ta[4];
#pragma unroll
            for (int r = 0; r < 4; ++r) { t[r] = bx_s[j0 + r]; ta[r] = ar_s[j0 + r]; }
#pragma unroll
            for (int r = 0; r < 4; ++r) {
                int j = j0 + r;
                if (j < nc - 1 && lane > j && lane < nc &&
                    iou_gt(bx.x, bx.y, bx.z, bx.w,
                           t[r].x, t[r].y, t[r].z, t[r].w, ta[r]))
                    ov |= 1ull << j;
            }
        }
        uint64_t alive = (nc >= 64) ? ~0ull : ((1ull << nc) - 1ull);
        for (int t = 0; t < nc; ++t) {
            if (!((alive >> t) & 1ull)) continue;
            uint64_t die = __ballot(((ov >> t) & 1ull) != 0);
            alive &= ~die;
        }
        int nk = __popcll(alive);
        if (lane < nc && ((alive >> lane) & 1ull))
            ks[__popcll(alive & lmask)] = key;
        if (lane == 0) knum[bc] = nk;
    } else if (nc <= 128) {
        // ---- medium path: two-register descending bitonic of 128 u64 keys
        uint64_t kA = (lane < nc) ? mem[lane] : 0ull;
        uint64_t kB = (64 + lane < nc) ? mem[64 + lane] : 0ull;
        for (int k = 2; k <= 128; k <<= 1) {
            bool up0 = ((lane & k) == 0);
            bool up1 = (((64 + lane) & k) == 0);
            for (int j = k >> 1; j >= 1; j >>= 1) {
                if (j == 64) {
                    ce64(kA, kB, up0);   // k==128 here: up0 == true
                } else {
                    uint64_t wA = shfl_xor64(kA, j);
                    uint64_t wB = shfl_xor64(kB, j);
                    bool kmA = (((lane & j) == 0) == up0);
                    bool kmB = (((lane & j) == 0) == up1);
                    kA = kmA ? (kA > wA ? kA : wA) : (kA < wA ? kA : wA);
                    kB = kmB ? (kB > wB ? kB : wB) : (kB < wB ? kB : wB);
                }
            }
        }
        const int mB = 64 + lane;
        unsigned idxA = (unsigned)kA, idxB = (unsigned)kB;
        float4 bA = make_float4(0, 0, 0, 0), bB = bA;
        float  aA = 0.0f, aB = 0.0f;
        if (lane < nc) {
            bA = boxes4[bN + idxA];
            {
#pragma clang fp contract(off)
                aA = (bA.z - bA.x) * (bA.w - bA.y);
            }
        }
        if (mB < nc) {
            bB = boxes4[bN + idxB];
            {
#pragma clang fp contract(off)
                aB = (bB.z - bB.x) * (bB.w - bB.y);
            }
        }
        bx_s[lane] = bA;      ar_s[lane] = aA;
        bx_s[64 + lane] = bB; ar_s[64 + lane] = aB;
        __syncthreads();
        uint64_t ovA0 = 0, ovB0 = 0, ovB1 = 0;
        for (int j0 = 0; j0 < nc - 1; j0 += 4) {
            float4 t[4]; float ta[4];
#pragma unroll
            for (int r = 0; r < 4; ++r) { t[r] = bx_s[j0 + r]; ta[r] = ar_s[j0 + r]; }
#pragma unroll
            for (int r = 0; r < 4; ++r) {
                int j = j0 + r;
                if (j >= nc - 1) continue;
                if (j < 64) {
                    if (lane > j && lane < nc &&
                        iou_gt(bA.x, bA.y, bA.z, bA.w, t[r].x, t[r].y, t[r].z, t[r].w, ta[r]))
                        ovA0 |= 1ull << j;
                    if (mB < nc &&
                        iou_gt(bB.x, bB.y, bB.z, bB.w, t[r].x, t[r].y, t[r].z, t[r].w, ta[r]))
                        ovB0 |= 1ull << j;
                } else {
                    if (mB > j && mB < nc &&
                        iou_gt(bB.x, bB.y, bB.z, bB.w, t[r].x, t[r].y, t[r].z, t[r].w, ta[r]))
                        ovB1 |= 1ull << (j - 64);
                }
            }
        }
        uint64_t alive0 = (nc >= 64) ? ~0ull : ((1ull << nc) - 1ull);
        uint64_t alive1 = (nc >= 128) ? ~0ull : ((1ull << (nc - 64)) - 1ull);
        for (int t = 0; t < nc; ++t) {
            if (t < 64) {
                if (!((alive0 >> t) & 1ull)) continue;
                uint64_t d0 = __ballot(((ovA0 >> t) & 1ull) != 0);
                uint64_t d1 = __ballot(((ovB0 >> t) & 1ull) != 0);
                alive0 &= ~d0;
                alive1 &= ~d1;
            } else {
                int tt = t - 64;
                if (!((alive1 >> tt) & 1ull)) continue;
                uint64_t d1 = __ballot(((ovB1 >> tt) & 1ull) != 0);
                alive1 &= ~d1;
            }
        }
        int c0 = __popcll(alive0);
        int nk = c0 + __popcll(alive1);
        if (lane < nc && ((alive0 >> lane) & 1ull))
            ks[__popcll(alive0 & lmask)] = kA;
        if (mB < nc && ((alive1 >> lane) & 1ull))
            ks[c0 + __popcll(alive1 & lmask)] = kB;
        if (lane == 0) knum[bc] = nk;
    } else {
        // ---- generic fallback (nc in 129..160; statistically never taken)
        for (int r = 0; r < nc; ++r) {             // odd-even sort, descending
            int st = r & 1;
            for (int m = st + 2 * lane; m + 1 < nc; m += 128) {
                uint64_t x = mem[m], y = mem[m + 1];
                if (x < y) { mem[m] = y; mem[m + 1] = x; }
            }
            __syncthreads();
        }
        float4 bx0 = make_float4(0, 0, 0, 0), bx1 = bx0, bx2 = bx0, bx3 = bx0;
        {
            int m = lane;
            if (m < nc) bx0 = boxes4[bN + (unsigned)mem[m]];
            m = 64 + lane;
            if (m < nc) bx1 = boxes4[bN + (unsigned)mem[m]];
            m = 128 + lane;
            if (m < nc) bx2 = boxes4[bN + (unsigned)mem[m]];
        }
        uint64_t supp = 0;
        int jmaxc = (nc + 63) >> 6;
        for (int t = 0; t < nc; ++t) {
            int jt = t >> 6, lt = t & 63;
            uint64_t am = __ballot(((supp >> jt) & 1ull) == 0);
            if (!((am >> lt) & 1ull)) continue;
            float4 sr = (jt == 0) ? bx0 : (jt == 1) ? bx1 : (jt == 2) ? bx2 : bx3;
            float t0 = __shfl(sr.x, lt), t1 = __shfl(sr.y, lt);
            float t2 = __shfl(sr.z, lt), t3 = __shfl(sr.w, lt);
            if (lane == 0) atomicOr(&keepw[jt], 1ull << lt);
            float tarea;
            {
#pragma clang fp contract(off)
                tarea = (t2 - t0) * (t3 - t1);
            }
            for (int j = jt; j < jmaxc; ++j) {
                int m = (j << 6) + lane;
                if (m <= t || m >= nc) continue;
                if ((supp >> j) & 1ull) continue;
                float4 cr = (j == 0) ? bx0 : (j == 1) ? bx1 : (j == 2) ? bx2 : bx3;
                if (iou_gt(cr.x, cr.y, cr.z, cr.w, t0, t1, t2, t3, tarea))
                    supp |= (1ull << j);
            }
        }
        __syncthreads();
        uint64_t w0 = keepw[0], w1 = keepw[1], w2 = keepw[2];
        int c0 = __popcll(w0), c1 = __popcll(w1);
        int nk = c0 + c1 + __popcll(w2);
        if ((w0 >> lane) & 1ull)
            ks[__popcll(w0 & lmask)] = mem[lane];
        if (64 + lane < nc && ((w1 >> lane) & 1ull))
            ks[c0 + __popcll(w1 & lmask)] = mem[64 + lane];
        if (128 + lane < nc && ((w2 >> lane) & 1ull))
            ks[c0 + c1 + __popcll(w2 & lmask)] = mem[128 + lane];
        if (lane == 0) knum[bc] = nk;
    }
}

// ===== K2: per-batch top-300 selection (histogram) + 1024-key sort + pack ======
// Reads the 80 per-class segments once into LDS (dense[]), then histogram /
// cutoff / gather / bitonic sort run entirely out of LDS.
__global__ __launch_bounds__(256)
void k2_pack(const float* __restrict__ scores,
             const float* __restrict__ boxes,
             const int*   __restrict__ classes,
             const uint64_t* __restrict__ kseg,
             const int*      __restrict__ knum,
             float* __restrict__ out)
{
    const int b    = blockIdx.x;
    const int tid  = threadIdx.x;
    const int lane = tid & 63;
    const int wv   = tid >> 6;
    const int bN   = b * NN;

    __shared__ int      hist[256];
    __shared__ uint64_t cand[1024];
    __shared__ uint64_t dense[NN];
    __shared__ int      nks[NCLS];
    __shared__ int      pre[NCLS + 1];
    __shared__ int      ncand_s, cutoff_s;

    if (tid < NCLS) nks[tid] = knum[b * NCLS + tid];

    // static output fills (harness poisons d_out before every timed replay)
    for (int s = tid; s < MAXDET; s += 256) {
        out[OFF_IDX + b * MAXDET + s] = -1.0f;
        out[OFF_SCR + b * MAXDET + s] = 0.0f;
        int ob = OFF_BOX + (b * MAXDET + s) * 4;
        out[ob + 0] = 0.0f; out[ob + 1] = 0.0f;
        out[ob + 2] = 0.0f; out[ob + 3] = 0.0f;
        out[OFF_CLS + b * MAXDET + s] = 0.0f;
    }
    hist[tid] = 0;
    if (tid == 0) { ncand_s = 0; cutoff_s = 256; }
    __syncthreads();

    if (tid == 0) {
        int acc = 0;
        for (int c2 = 0; c2 < NCLS; ++c2) { pre[c2] = acc; acc += nks[c2]; }
        pre[NCLS] = acc;
    }
    __syncthreads();
    const int kept_n = pre[NCLS];
    const int target = kept_n < MAXDET ? kept_n : MAXDET;

    // stage all kept keys into LDS (one global pass; segments are disjoint)
    for (int c2 = wv; c2 < NCLS; c2 += 4) {
        const uint64_t* seg = kseg + (uint64_t)(b * NCLS + c2) * CAP;
        const int base0 = pre[c2], n = nks[c2];
        for (int i = lane; i < n; i += 64)
            dense[base0 + i] = seg[i];
    }
    __syncthreads();

    // histogram of kept scores by value bucket (uniform scores -> ~14/bin)
    for (int i = tid; i < kept_n; i += 256) {
        unsigned m = (unsigned)(dense[i] >> 32);
        float f = __uint_as_float(m & 0x7FFFFFFFu);   // valid scores are positive
        int bin = (int)(f * 256.0f);
        bin = bin > 255 ? 255 : bin;
        atomicAdd(&hist[bin], 1);
    }
    __syncthreads();

    // suffix sums over 64 groups of 4 bins; pick coarsest cutoff with >= target
    if (wv == 0) {
        int g = lane;
        int cg = hist[4 * g] + hist[4 * g + 1] + hist[4 * g + 2] + hist[4 * g + 3];
        int s = cg;
        for (int off = 1; off < 64; off <<= 1) {
            int t = __shfl_down(s, off, 64);
            if (lane + off < 64) s += t;
        }
        int snext = __shfl_down(s, 1, 64);
        if (lane == 63) snext = 0;
        if (target > 0 && s >= target && snext < target) cutoff_s = 4 * g;
    }
    __syncthreads();
    const int cutoff = cutoff_s;

    // gather candidate keys (bins >= cutoff): count in [target, target+~100]
    for (int i = tid; i < kept_n; i += 256) {
        uint64_t key = dense[i];
        unsigned m = (unsigned)(key >> 32);
        float f = __uint_as_float(m & 0x7FFFFFFFu);
        int bin = (int)(f * 256.0f);
        bin = bin > 255 ? 255 : bin;
        if (bin >= cutoff) {
            int slot = atomicAdd(&ncand_s, 1);
            if (slot < 1024) cand[slot] = key;
        }
    }
    __syncthreads();
    const int ncand = ncand_s < 1024 ? ncand_s : 1024;
    for (int i = tid; i < 1024; i += 256)
        if (i >= ncand) cand[i] = 0ull;
    __syncthreads();

    // descending bitonic sort of 1024 u64 keys (256 thr x 4 elems)
    // i bits: [1:0]=e (register), [7:2]=lane (shfl), [9:8]=wave (LDS)
    const int base = tid << 2;
    uint64_t v[4];
#pragma unroll
    for (int e = 0; e < 4; ++e) v[e] = cand[base + e];
    for (int k = 2; k <= 1024; k <<= 1) {
        for (int j = k >> 1; j >= 1; j >>= 1) {
            if (j >= 256) {
                __syncthreads();
#pragma unroll
                for (int e = 0; e < 4; ++e) cand[base + e] = v[e];
                __syncthreads();
                const int pb = base ^ j;
                const bool keepmax = (((base & j) == 0) == ((base & k) == 0));
                uint64_t w[4];
#pragma unroll
                for (int e = 0; e < 4; ++e) w[e] = cand[pb + e];
#pragma unroll
                for (int e = 0; e < 4; ++e) {
                    uint64_t a = v[e], c = w[e];
                    v[e] = keepmax ? (a > c ? a : c) : (a < c ? a : c);
                }
            } else if (j >= 4) {
                const int m = j >> 2;
                const bool keepmax = (((lane & m) == 0) == ((base & k) == 0));
                unsigned wlo[4], whi[4];
#pragma unroll
                for (int e = 0; e < 4; ++e) wlo[e] = __shfl_xor((unsigned)v[e], m, 64);
#pragma unroll
                for (int e = 0; e < 4; ++e) whi[e] = __shfl_xor((unsigned)(v[e] >> 32), m, 64);
#pragma unroll
                for (int e = 0; e < 4; ++e) {
                    uint64_t w = ((uint64_t)whi[e] << 32) | wlo[e];
                    uint64_t a = v[e];
                    v[e] = keepmax ? (a > w ? a : w) : (a < w ? a : w);
                }
            } else if (j == 2) {
                bool d = ((base & k) == 0);
                ce64(v[0], v[2], d);
                ce64(v[1], v[3], d);
            } else {
                bool d0 = (((base + 0) & k) == 0);
                bool d2 = (((base + 2) & k) == 0);
                ce64(v[0], v[1], d0);
                ce64(v[2], v[3], d2);
            }
        }
    }

    // write top-target detections (rank = sorted position)
    const float4* boxes4 = (const float4*)boxes;
#pragma unroll
    for (int e = 0; e < 4; ++e) {
        int rank = base + e;
        if (rank < target) {
            unsigned idx = (unsigned)v[e];
            out[OFF_SCR + b * MAXDET + rank] = scores[bN + idx];
            float4 g = boxes4[bN + idx];
            int ob = OFF_BOX + (b * MAXDET + rank) * 4;
            out[ob + 0] = g.x; out[ob + 1] = g.y;
            out[ob + 2] = g.z; out[ob + 3] = g.w;
            out[OFF_CLS + b * MAXDET + rank] = (float)classes[bN + idx];
        }
    }
    if (tid == 0) out[OFF_NDT + b] = (float)target;
}

extern "C" void kernel_launch(void* const* d_in, const int* in_sizes, int n_in,
                              void* d_out, int out_size, void* d_ws, size_t ws_size,
                              hipStream_t stream)
{
    const float* scores  = (const float*)d_in[0];
    const float* boxes   = (const float*)d_in[1];
    const int*   classes = (const int*)d_in[2];
    float*       out     = (float*)d_out;

    char* ws = (char*)d_ws;
    uint64_t* kseg = (uint64_t*)(ws + WS_KSEG);
    int*      knum = (int*)(ws + WS_KNUM);

    hipLaunchKernelGGL(k1_bin_nms, dim3(NB * NCLS), dim3(64), 0, stream,
                       scores, boxes, classes, kseg, knum);
    hipLaunchKernelGGL(k2_pack, dim3(NB), dim3(256), 0, stream,
                       scores, boxes, classes, kseg, knum, out);
}